// Round 1
// baseline (344.823 us; speedup 1.0000x reference)
//
#include <hip/hip_runtime.h>
#include <stdint.h>
#include <stddef.h>

// MetaLSTMCell: B=512, I=1024, H=1024, HH=256, E=64, T=4
// Stage 1: meta LSTM   -> meta_h_new, meta_c_new      (MFMA bf16)
// Stage 2: z = mh'@Wz^T (tiny, f32 vector)
// Stage 3: main pre + gates -> main_h_new, main_c_new (MFMA bf16)

using f32x4  = __attribute__((ext_vector_type(4))) float;
using bf16x8 = __attribute__((ext_vector_type(8))) short;

__device__ __forceinline__ unsigned short f2bf(float x) {
  union { float f; unsigned u; } v; v.f = x;
  unsigned r = v.u + 0x7fffu + ((v.u >> 16) & 1u);  // RNE
  return (unsigned short)(r >> 16);
}

__device__ __forceinline__ float sigf(float x) { return 1.0f / (1.0f + __expf(-x)); }

// ---------------- LDS staging ----------------
// A tile: 64 rows x 32 cols bf16, row stride 40 ushorts (80B) -> 2-way bank alias only.
__device__ __forceinline__ void stage_a64(unsigned short (*la)[40], const float* __restrict__ A,
                                          int lda, int m0, int col, int tid) {
  const int r = tid >> 2;
  const int c = (tid & 3) * 8;
  const float* p = A + (size_t)(m0 + r) * lda + col + c;
#pragma unroll
  for (int q = 0; q < 2; ++q) {
    f32x4 v = *(const f32x4*)(p + q * 4);
    ushort4 s = make_ushort4(f2bf(v[0]), f2bf(v[1]), f2bf(v[2]), f2bf(v[3]));
    *(ushort4*)&la[r][c + q * 4] = s;
  }
}

// W tile: NROWS rows (4 gates x NT output-cols) x 32 cols bf16.
// tile row t = g*NT + j  <->  weight row g*gstride + n0 + j
template <int NROWS>
__device__ __forceinline__ void stage_w(unsigned short (*lw)[40], const float* __restrict__ W,
                                        int ldw, int gstride, int n0, int col, int tid) {
  constexpr int EPT = NROWS * 32 / 256;  // elems per thread (8 or 16)
  constexpr int TPR = 32 / EPT;          // threads per row
  constexpr int NT  = NROWS / 4;
  const int r = tid / TPR;
  const int c = (tid % TPR) * EPT;
  const int g = r / NT;
  const int j = r - g * NT;
  const float* p = W + (size_t)(g * gstride + n0 + j) * ldw + col + c;
#pragma unroll
  for (int q = 0; q < EPT / 4; ++q) {
    f32x4 v = *(const f32x4*)(p + q * 4);
    ushort4 s = make_ushort4(f2bf(v[0]), f2bf(v[1]), f2bf(v[2]), f2bf(v[3]));
    *(ushort4*)&lw[r][c + q * 4] = s;
  }
}

// MFMA fragment: row = rbase + (lane&15), 8 contiguous bf16 at k-chunk (lane>>4)*8.
__device__ __forceinline__ bf16x8 frag(const unsigned short (*l)[40], int rbase, int lane) {
  return *(const bf16x8*)&l[rbase + (lane & 15)][(lane >> 4) * 8];
}

// One GEMM segment: acc[g*NJ+j] += A[m0..+64, acol..acol+K) @ W(rows g*gstride+n0+j, wcol..wcol+K)^T
// Block = 256 thr = 4 waves; wave wid owns m-rows wid*16..+16.
template <int NWROWS, int NJ>
__device__ __forceinline__ void gemm_seg(f32x4* acc, unsigned short (*la)[40], unsigned short (*lw)[40],
                                         const float* __restrict__ A, int lda, int acol, int K,
                                         const float* __restrict__ W, int ldw, int wcol,
                                         int gstride, int n0, int m0, int tid, int lane, int wid) {
  for (int k0 = 0; k0 < K; k0 += 32) {
    __syncthreads();
    stage_a64(la, A, lda, m0, acol + k0, tid);
    stage_w<NWROWS>(lw, W, ldw, gstride, n0, wcol + k0, tid);
    __syncthreads();
    bf16x8 af = frag(la, wid * 16, lane);
#pragma unroll
    for (int g = 0; g < 4; ++g) {
#pragma unroll
      for (int j = 0; j < NJ; ++j) {
        bf16x8 wf = frag(lw, (g * NJ + j) * 16, lane);
        acc[g * NJ + j] = __builtin_amdgcn_mfma_f32_16x16x32_bf16(af, wf, acc[g * NJ + j], 0, 0, 0);
      }
    }
  }
}

// ---------------- Kernel 1: meta LSTM ----------------
// grid (8, 16): m-tile 64, hh-tile 16 (x4 gates = 64 W rows). Gate fused in-register.
__launch_bounds__(256)
__global__ void meta_kernel(const float* __restrict__ input, const float* __restrict__ main_h,
                            const float* __restrict__ meta_h_in, const float* __restrict__ meta_c_in,
                            const float* __restrict__ w_ih, const float* __restrict__ w_hh,
                            const float* __restrict__ bias_hyper,
                            float* __restrict__ out_meta_h, float* __restrict__ out_meta_c,
                            float* __restrict__ ws_meta_h) {
  __shared__ unsigned short la[64][40];
  __shared__ unsigned short lw[64][40];
  const int tid = threadIdx.x, lane = tid & 63, wid = tid >> 6;
  const int m0 = blockIdx.x * 64, hh0 = blockIdx.y * 16;

  f32x4 acc[4];
  f32x4 z4 = {0.f, 0.f, 0.f, 0.f};
#pragma unroll
  for (int f = 0; f < 4; ++f) acc[f] = z4;

  // meta_pre = [input | main_h] @ w_ih^T + meta_h @ w_hh^T
  gemm_seg<64, 1>(acc, la, lw, input,     1024, 0, 1024, w_ih, 2048, 0,    256, hh0, m0, tid, lane, wid);
  gemm_seg<64, 1>(acc, la, lw, main_h,    1024, 0, 1024, w_ih, 2048, 1024, 256, hh0, m0, tid, lane, wid);
  gemm_seg<64, 1>(acc, la, lw, meta_h_in,  256, 0,  256, w_hh,  256, 0,    256, hh0, m0, tid, lane, wid);

  const int col = lane & 15, rg = lane >> 4;
  const int hh = hh0 + col;
  const int mbase = m0 + wid * 16 + rg * 4;
  const float bi = bias_hyper[hh],       bfv = bias_hyper[256 + hh];
  const float bg = bias_hyper[512 + hh], bo  = bias_hyper[768 + hh];
#pragma unroll
  for (int r = 0; r < 4; ++r) {
    const int m = mbase + r;
    const float mi = acc[0][r] + bi, mf = acc[1][r] + bfv;
    const float mg = acc[2][r] + bg, mo = acc[3][r] + bo;
    const float c = sigf(mf) * meta_c_in[m * 256 + hh] + sigf(mi) * tanhf(mg);
    const float h = sigf(mo) * tanhf(c);
    out_meta_c[m * 256 + hh] = c;
    out_meta_h[m * 256 + hh] = h;
    ws_meta_h[m * 256 + hh]  = h;
  }
}

// ---------------- Kernel 2: z embeddings ----------------
// z[b][0:64]=zi, [64:128]=zH, [128:192]=zb.  grid 64 blocks x 192 thr, 8 b-rows per block.
__global__ void z_kernel(const float* __restrict__ mh, const float* __restrict__ w_hzi,
                         const float* __restrict__ w_hzH, const float* __restrict__ w_hzb,
                         const float* __restrict__ bias_i, const float* __restrict__ bias_H,
                         float* __restrict__ z) {
  __shared__ float sm[8][256];
  const int t = threadIdx.x;
  const int b0 = blockIdx.x * 8;
  for (int i = t; i < 8 * 256; i += 192) sm[i >> 8][i & 255] = mh[b0 * 256 + i];
  __syncthreads();
  const int g = t >> 6, n = t & 63;
  const float* w = (g == 0 ? w_hzi : g == 1 ? w_hzH : w_hzb) + n * 256;
  const float bias = (g == 0 ? bias_i[n] : g == 1 ? bias_H[n] : 0.0f);
  float acc[8];
#pragma unroll
  for (int r = 0; r < 8; ++r) acc[r] = bias;
  for (int k = 0; k < 256; k += 4) {
    f32x4 wv = *(const f32x4*)(w + k);
#pragma unroll
    for (int r = 0; r < 8; ++r)
      acc[r] += sm[r][k] * wv[0] + sm[r][k + 1] * wv[1] + sm[r][k + 2] * wv[2] + sm[r][k + 3] * wv[3];
  }
#pragma unroll
  for (int r = 0; r < 8; ++r) z[(size_t)(b0 + r) * 192 + t] = acc[r];
}

// ---------------- Kernel 3: main pre + gates ----------------
// grid (8, 32): m-tile 64, h-tile 32 (x4 gates = 128 W rows).
// pre = (zi@D_i^T)*(x@W_iH^T) + (zH@D_H^T)*(h@W_HH^T) + zb@B^T + bias
__launch_bounds__(256)
__global__ void main_kernel(const float* __restrict__ input, const float* __restrict__ main_h,
                            const float* __restrict__ main_c, const int* __restrict__ task_ptr,
                            const float* __restrict__ weight_iH, const float* __restrict__ weight_HH,
                            const float* __restrict__ w_dziH, const float* __restrict__ w_dzHH,
                            const float* __restrict__ w_bzH, const float* __restrict__ bias4h,
                            const float* __restrict__ z,
                            float* __restrict__ out_h, float* __restrict__ out_c) {
  __shared__ unsigned short la[64][40];
  __shared__ unsigned short lw[128][40];
  const int tid = threadIdx.x, lane = tid & 63, wid = tid >> 6;
  const int m0 = blockIdx.x * 64, h0 = blockIdx.y * 32;
  const int task = task_ptr[0];
  const float* WiH = weight_iH + (size_t)task * 4096 * 1024;
  const float* WHH = weight_HH + (size_t)task * 4096 * 1024;

  f32x4 a[8], d[8], p[8];
  f32x4 z4 = {0.f, 0.f, 0.f, 0.f};
#pragma unroll
  for (int f = 0; f < 8; ++f) { a[f] = z4; d[f] = z4; }

  // p = (x @ WiH^T) * (zi @ dziH^T)
  gemm_seg<128, 2>(a, la, lw, input, 1024, 0, 1024, WiH,    1024, 0, 1024, h0, m0, tid, lane, wid);
  gemm_seg<128, 2>(d, la, lw, z,      192, 0,   64, w_dziH,   64, 0, 1024, h0, m0, tid, lane, wid);
#pragma unroll
  for (int f = 0; f < 8; ++f) { p[f] = a[f] * d[f]; a[f] = z4; d[f] = z4; }

  // p += (h @ WHH^T) * (zH @ dzHH^T)
  gemm_seg<128, 2>(a, la, lw, main_h, 1024,  0, 1024, WHH,    1024, 0, 1024, h0, m0, tid, lane, wid);
  gemm_seg<128, 2>(d, la, lw, z,      192,  64,   64, w_dzHH,   64, 0, 1024, h0, m0, tid, lane, wid);
#pragma unroll
  for (int f = 0; f < 8; ++f) { p[f] += a[f] * d[f]; d[f] = z4; }

  // p += zb @ bzH^T
  gemm_seg<128, 2>(d, la, lw, z,      192, 128,   64, w_bzH,    64, 0, 1024, h0, m0, tid, lane, wid);
#pragma unroll
  for (int f = 0; f < 8; ++f) p[f] += d[f];

  const int col = lane & 15, rg = lane >> 4;
  const int mbase = m0 + wid * 16 + rg * 4;
#pragma unroll
  for (int j = 0; j < 2; ++j) {
    const int h = h0 + j * 16 + col;
    const float b0 = bias4h[h],        b1 = bias4h[1024 + h];
    const float b2 = bias4h[2048 + h], b3 = bias4h[3072 + h];
#pragma unroll
    for (int r = 0; r < 4; ++r) {
      const int m = mbase + r;
      const float gi = p[0 * 2 + j][r] + b0;
      const float gf = p[1 * 2 + j][r] + b1;
      const float gg = p[2 * 2 + j][r] + b2;
      const float go = p[3 * 2 + j][r] + b3;
      const float c  = sigf(gf) * main_c[m * 1024 + h] + sigf(gi) * tanhf(gg);
      const float hn = sigf(go) * tanhf(c);
      out_c[m * 1024 + h] = c;
      out_h[m * 1024 + h] = hn;
    }
  }
}

extern "C" void kernel_launch(void* const* d_in, const int* in_sizes, int n_in,
                              void* d_out, int out_size, void* d_ws, size_t ws_size,
                              hipStream_t stream) {
  const float* input      = (const float*)d_in[0];
  const float* main_h     = (const float*)d_in[1];
  const float* main_c     = (const float*)d_in[2];
  const float* meta_h     = (const float*)d_in[3];
  const float* meta_c     = (const float*)d_in[4];
  const int*   task_index = (const int*)d_in[5];
  const float* weight_iH  = (const float*)d_in[6];
  const float* weight_HH  = (const float*)d_in[7];
  const float* weight_ih  = (const float*)d_in[8];
  const float* weight_hh  = (const float*)d_in[9];
  const float* w_hzi      = (const float*)d_in[10];
  const float* w_hzH      = (const float*)d_in[11];
  const float* w_hzb      = (const float*)d_in[12];
  const float* w_dziH     = (const float*)d_in[13];
  const float* w_dzHH     = (const float*)d_in[14];
  const float* w_bzH      = (const float*)d_in[15];
  const float* bias_i     = (const float*)d_in[16];
  const float* bias_H     = (const float*)d_in[17];
  const float* bias       = (const float*)d_in[18];
  const float* bias_hyper = (const float*)d_in[19];

  float* out        = (float*)d_out;
  float* out_main_h = out;
  float* out_main_c = out + 512 * 1024;
  float* out_meta_h = out + 2 * 512 * 1024;
  float* out_meta_c = out + 2 * 512 * 1024 + 512 * 256;

  float* z          = (float*)d_ws;            // [512][192]
  float* ws_meta_h  = z + 512 * 192;           // [512][256]

  meta_kernel<<<dim3(8, 16), 256, 0, stream>>>(input, main_h, meta_h, meta_c,
                                               weight_ih, weight_hh, bias_hyper,
                                               out_meta_h, out_meta_c, ws_meta_h);
  z_kernel<<<dim3(64), 192, 0, stream>>>(ws_meta_h, w_hzi, w_hzH, w_hzb, bias_i, bias_H, z);
  main_kernel<<<dim3(8, 32), 256, 0, stream>>>(input, main_h, main_c, task_index,
                                               weight_iH, weight_HH, w_dziH, w_dzHH, w_bzH,
                                               bias, z, out_main_h, out_main_c);
}

// Round 5
// 254.591 us; speedup vs baseline: 1.3544x; 1.3544x over previous
//
#include <hip/hip_runtime.h>
#include <stdint.h>
#include <stddef.h>

// MetaLSTMCell B=512, I=1024, H=1024, HH=256, E=64, T=4
// Pipeline: convert(all operands -> bf16 in ws) -> meta LSTM -> z -> main LSTM
// GEMM scheme: A-tile staged to LDS chunk-major via global_load_lds (dbuf, 1 barrier/step),
// W fragments loaded direct global->VGPR (L2-resident, XCD-grouped swizzle),
// wave g owns gate g; gates recombined through LDS for fused epilogue.

using f32x4    = __attribute__((ext_vector_type(4))) float;
using bf16x8   = __attribute__((ext_vector_type(8))) short;
using ushort8v = __attribute__((ext_vector_type(8))) unsigned short;

// ws layout (ushort element offsets)
#define XH_OFF   0u          // [512][2304]  = input | main_h | meta_h
#define WCAT_OFF 1179648u    // [1024][2304] = w_ih | w_hh
#define W1_OFF   3538944u    // [4096][1024] = weight_iH[task]
#define W2_OFF   7733248u    // [4096][1024] = weight_HH[task]
#define D1_OFF   11927552u   // [4096][64] = w_dziH
#define D2_OFF   12189696u   // [4096][64] = w_dzHH
#define D3_OFF   12451840u   // [4096][64] = w_bzH
#define MH_OFF   12713984u   // [512][256]  meta_h_new (bf16)
#define ZB_OFF   12845056u   // [512][192]  zi|zH|zb (bf16, bias folded)

__device__ __forceinline__ unsigned short f2bf(float x) {
  union { float f; unsigned u; } v; v.f = x;
  unsigned r = v.u + 0x7fffu + ((v.u >> 16) & 1u);  // RNE
  return (unsigned short)(r >> 16);
}
__device__ __forceinline__ float bf2f(unsigned short u) {
  union { unsigned u32; float f; } v; v.u32 = ((unsigned)u) << 16; return v.f;
}
__device__ __forceinline__ float sigf(float x) { return 1.0f / (1.0f + __expf(-x)); }

// async global->LDS, 16B per lane; lds must be the wave-uniform base.
__device__ __forceinline__ void gload16(unsigned short* lds, const unsigned short* g) {
  __builtin_amdgcn_global_load_lds((const __attribute__((address_space(1))) void*)g,
                                   (__attribute__((address_space(3))) void*)lds,
                                   16, 0, 0);
}

// ---------------- convert: f32 -> bf16 into ws ----------------
template <int CV8>
__device__ __forceinline__ void cvt_job(const float* __restrict__ src, int ss,
                                        unsigned short* __restrict__ dst, int ds, int v) {
  const int r = v / CV8;
  const int c = (v - r * CV8) * 8;
  const float* p = src + (size_t)r * ss + c;
  f32x4 x = *(const f32x4*)p;
  f32x4 y = *(const f32x4*)(p + 4);
  ushort8v o;
  o[0] = f2bf(x[0]); o[1] = f2bf(x[1]); o[2] = f2bf(x[2]); o[3] = f2bf(x[3]);
  o[4] = f2bf(y[0]); o[5] = f2bf(y[1]); o[6] = f2bf(y[2]); o[7] = f2bf(y[3]);
  *(ushort8v*)(dst + (size_t)r * ds + c) = o;
}

__global__ __launch_bounds__(256) void convert_kernel(
    const float* __restrict__ input, const float* __restrict__ main_h,
    const float* __restrict__ meta_h, const float* __restrict__ w_ih,
    const float* __restrict__ w_hh, const float* __restrict__ wiH,
    const float* __restrict__ wHH, const int* __restrict__ task_ptr,
    const float* __restrict__ d1, const float* __restrict__ d2,
    const float* __restrict__ d3, unsigned short* __restrict__ ws) {
  const int b = blockIdx.x, t = threadIdx.x;
  if (b < 576) {
    if (b < 256)      cvt_job<128>(input,  1024, ws + XH_OFF,        2304, b * 256 + t);
    else if (b < 512) cvt_job<128>(main_h, 1024, ws + XH_OFF + 1024, 2304, (b - 256) * 256 + t);
    else              cvt_job<32>(meta_h,   256, ws + XH_OFF + 2048, 2304, (b - 512) * 256 + t);
  } else if (b < 1728) {
    if (b < 1600) cvt_job<256>(w_ih, 2048, ws + WCAT_OFF,        2304, (b - 576) * 256 + t);
    else          cvt_job<32>(w_hh,   256, ws + WCAT_OFF + 2048, 2304, (b - 1600) * 256 + t);
  } else if (b < 5824) {
    const int task = task_ptr[0];
    if (b < 3776) cvt_job<128>(wiH + (size_t)task * 4194304, 1024, ws + W1_OFF, 1024, (b - 1728) * 256 + t);
    else          cvt_job<128>(wHH + (size_t)task * 4194304, 1024, ws + W2_OFF, 1024, (b - 3776) * 256 + t);
  } else {
    if (b < 5952)      cvt_job<8>(d1, 64, ws + D1_OFF, 64, (b - 5824) * 256 + t);
    else if (b < 6080) cvt_job<8>(d2, 64, ws + D2_OFF, 64, (b - 5952) * 256 + t);
    else               cvt_job<8>(d3, 64, ws + D3_OFF, 64, (b - 6080) * 256 + t);
  }
}

// ---------------- meta LSTM ----------------
// grid 256: m-tile 32, hh-tile 16. wave g = gate g. A=xh [512][2304], W=wcat [1024][2304].
__global__ __launch_bounds__(256) void meta_kernel(
    unsigned short* __restrict__ ws, const float* __restrict__ meta_c_in,
    const float* __restrict__ bias_hyper,
    float* __restrict__ out_mh, float* __restrict__ out_mc) {
  __shared__ unsigned short lA[2][2048];  // [buf][chunk8][row32][8]
  __shared__ float sm[4][32][16];
  const int tid = threadIdx.x, lane = tid & 63, wid = tid >> 6;
  const int b = blockIdx.x, j = b >> 3;
  const int hh0 = ((b & 7) * 2 + (j & 1)) * 16;   // XCD-grouped hh tiles
  const int m0  = (j >> 1) * 32;

  const unsigned short* asrc = ws + XH_OFF + (size_t)(m0 + (lane & 31)) * 2304 + (wid * 2 + (lane >> 5)) * 8;
  unsigned short* adst0 = &lA[0][wid * 512];
  unsigned short* adst1 = &lA[1][wid * 512];
  const unsigned short* wp = ws + WCAT_OFF + (size_t)(wid * 256 + hh0 + (lane & 15)) * 2304 + (lane >> 4) * 8;

  f32x4 acc[2];
  acc[0] = f32x4{0.f, 0.f, 0.f, 0.f}; acc[1] = acc[0];

  gload16(adst0, asrc);
  __syncthreads();
  for (int t = 0; t < 36; ++t) {
    const unsigned short* curb = lA[t & 1];
    if (t + 1 < 36) gload16((t & 1) ? adst0 : adst1, asrc + (t + 1) * 64);
    const int k = t * 64;
    bf16x8 w0 = *(const bf16x8*)(wp + k);
    bf16x8 w1 = *(const bf16x8*)(wp + k + 32);
#pragma unroll
    for (int mf = 0; mf < 2; ++mf) {
      bf16x8 a0 = *(const bf16x8*)(curb + (((lane >> 4)) * 32 + mf * 16 + (lane & 15)) * 8);
      bf16x8 a1 = *(const bf16x8*)(curb + ((4 + (lane >> 4)) * 32 + mf * 16 + (lane & 15)) * 8);
      acc[mf] = __builtin_amdgcn_mfma_f32_16x16x32_bf16(a0, w0, acc[mf], 0, 0, 0);
      acc[mf] = __builtin_amdgcn_mfma_f32_16x16x32_bf16(a1, w1, acc[mf], 0, 0, 0);
    }
    __syncthreads();
  }
#pragma unroll
  for (int mf = 0; mf < 2; ++mf)
#pragma unroll
    for (int r = 0; r < 4; ++r)
      sm[wid][mf * 16 + (lane >> 4) * 4 + r][lane & 15] = acc[mf][r];
  __syncthreads();
#pragma unroll
  for (int i = 0; i < 2; ++i) {
    const int p = tid * 2 + i;
    const int m = p >> 4, hh = p & 15;
    const int gm = m0 + m, gh = hh0 + hh;
    const float mi  = sm[0][m][hh] + bias_hyper[gh];
    const float mf_ = sm[1][m][hh] + bias_hyper[256 + gh];
    const float mg  = sm[2][m][hh] + bias_hyper[512 + gh];
    const float mo  = sm[3][m][hh] + bias_hyper[768 + gh];
    const float c = sigf(mf_) * meta_c_in[gm * 256 + gh] + sigf(mi) * tanhf(mg);
    const float h = sigf(mo) * tanhf(c);
    out_mc[gm * 256 + gh] = c;
    out_mh[gm * 256 + gh] = h;
    ws[MH_OFF + gm * 256 + gh] = f2bf(h);
  }
}

// ---------------- z embeddings ----------------
// z[b][0:64]=zi+bias_i, [64:128]=zH+bias_H, [128:192]=zb. bf16 out.
__global__ void z_kernel(unsigned short* __restrict__ ws,
                         const float* __restrict__ w_hzi, const float* __restrict__ w_hzH,
                         const float* __restrict__ w_hzb,
                         const float* __restrict__ bias_i, const float* __restrict__ bias_H) {
  __shared__ unsigned short smh[4 * 256];
  const int t = threadIdx.x;
  const int b0 = blockIdx.x * 4;
  for (int i = t; i < 1024; i += 192) smh[i] = ws[MH_OFF + b0 * 256 + i];
  __syncthreads();
  const int g = t >> 6, n = t & 63;
  const float* w = (g == 0 ? w_hzi : g == 1 ? w_hzH : w_hzb) + n * 256;
  const float bias = (g == 0 ? bias_i[n] : g == 1 ? bias_H[n] : 0.0f);
  float acc[4] = {bias, bias, bias, bias};
  for (int k = 0; k < 256; k += 4) {
    f32x4 wv = *(const f32x4*)(w + k);
#pragma unroll
    for (int r = 0; r < 4; ++r)
      acc[r] += bf2f(smh[r * 256 + k]) * wv[0] + bf2f(smh[r * 256 + k + 1]) * wv[1]
              + bf2f(smh[r * 256 + k + 2]) * wv[2] + bf2f(smh[r * 256 + k + 3]) * wv[3];
  }
#pragma unroll
  for (int r = 0; r < 4; ++r) ws[ZB_OFF + (size_t)(b0 + r) * 192 + t] = f2bf(acc[r]);
}

// ---------------- main LSTM ----------------
// grid 256: m-tile 64, h-tile 32. wave g = gate g.
__global__ __launch_bounds__(256) void main_kernel(
    unsigned short* __restrict__ ws, const float* __restrict__ main_c,
    const float* __restrict__ bias4h,
    float* __restrict__ out_h, float* __restrict__ out_c) {
  __shared__ unsigned short lA[2][4096];  // [buf][chunk8][row64][8]
  __shared__ float sm[4][64][32];
  const int tid = threadIdx.x, lane = tid & 63, wid = tid >> 6;
  const int b = blockIdx.x, jj = b & 31;
  const int h0 = ((jj & 7) * 4 + (jj >> 3)) * 32;  // XCD-grouped h tiles
  const int m0 = (b >> 5) * 64;

  unsigned short* ad00 = &lA[0][wid * 512];
  unsigned short* ad01 = &lA[0][2048 + wid * 512];
  unsigned short* ad10 = &lA[1][wid * 512];
  unsigned short* ad11 = &lA[1][2048 + wid * 512];

  const int l15 = lane & 15, l4 = lane >> 4;

  auto run = [&](f32x4* acc, const unsigned short* Arow, const unsigned short* wp0,
                 const unsigned short* wp1, int NT) {
    gload16(ad00, Arow + wid * 8);
    gload16(ad01, Arow + 32 + wid * 8);
    __syncthreads();
    for (int t = 0; t < NT; ++t) {
      const unsigned short* curb = lA[t & 1];
      if (t + 1 < NT) {
        const unsigned short* s = Arow + (t + 1) * 64 + wid * 8;
        gload16((t & 1) ? ad00 : ad10, s);
        gload16((t & 1) ? ad01 : ad11, s + 32);
      }
      const int k = t * 64;
      bf16x8 w00 = *(const bf16x8*)(wp0 + k);
      bf16x8 w01 = *(const bf16x8*)(wp0 + k + 32);
      bf16x8 w10 = *(const bf16x8*)(wp1 + k);
      bf16x8 w11 = *(const bf16x8*)(wp1 + k + 32);
#pragma unroll
      for (int mf = 0; mf < 4; ++mf) {
        bf16x8 a0 = *(const bf16x8*)(curb + ((l4) * 64 + mf * 16 + l15) * 8);
        bf16x8 a1 = *(const bf16x8*)(curb + ((4 + l4) * 64 + mf * 16 + l15) * 8);
        acc[mf * 2 + 0] = __builtin_amdgcn_mfma_f32_16x16x32_bf16(a0, w00, acc[mf * 2 + 0], 0, 0, 0);
        acc[mf * 2 + 0] = __builtin_amdgcn_mfma_f32_16x16x32_bf16(a1, w01, acc[mf * 2 + 0], 0, 0, 0);
        acc[mf * 2 + 1] = __builtin_amdgcn_mfma_f32_16x16x32_bf16(a0, w10, acc[mf * 2 + 1], 0, 0, 0);
        acc[mf * 2 + 1] = __builtin_amdgcn_mfma_f32_16x16x32_bf16(a1, w11, acc[mf * 2 + 1], 0, 0, 0);
      }
      __syncthreads();
    }
  };

  const size_t wrow0 = (size_t)(wid * 1024 + h0 + l15);
  const size_t wrow1 = wrow0 + 16;
  const unsigned short* W1p = ws + W1_OFF;
  const unsigned short* W2p = ws + W2_OFF;
  const unsigned short* D1p = ws + D1_OFF;
  const unsigned short* D2p = ws + D2_OFF;
  const unsigned short* D3p = ws + D3_OFF;
  const unsigned short* AX = ws + XH_OFF + (size_t)(m0 + lane) * 2304;
  const unsigned short* AZ = ws + ZB_OFF + (size_t)(m0 + lane) * 192;

  f32x4 pa[8], pd[8], pp[8];
  const f32x4 z4 = {0.f, 0.f, 0.f, 0.f};

#pragma unroll
  for (int f = 0; f < 8; ++f) pa[f] = z4;
  run(pa, AX, W1p + wrow0 * 1024 + l4 * 8, W1p + wrow1 * 1024 + l4 * 8, 16);
#pragma unroll
  for (int f = 0; f < 8; ++f) pd[f] = z4;
  run(pd, AZ, D1p + wrow0 * 64 + l4 * 8, D1p + wrow1 * 64 + l4 * 8, 1);
#pragma unroll
  for (int f = 0; f < 8; ++f) pp[f] = pa[f] * pd[f];

#pragma unroll
  for (int f = 0; f < 8; ++f) pa[f] = z4;
  run(pa, AX + 1024, W2p + wrow0 * 1024 + l4 * 8, W2p + wrow1 * 1024 + l4 * 8, 16);
#pragma unroll
  for (int f = 0; f < 8; ++f) pd[f] = z4;
  run(pd, AZ + 64, D2p + wrow0 * 64 + l4 * 8, D2p + wrow1 * 64 + l4 * 8, 1);
#pragma unroll
  for (int f = 0; f < 8; ++f) pp[f] += pa[f] * pd[f];

#pragma unroll
  for (int f = 0; f < 8; ++f) pd[f] = z4;
  run(pd, AZ + 128, D3p + wrow0 * 64 + l4 * 8, D3p + wrow1 * 64 + l4 * 8, 1);
#pragma unroll
  for (int f = 0; f < 8; ++f) pp[f] += pd[f];

#pragma unroll
  for (int mf = 0; mf < 4; ++mf)
#pragma unroll
    for (int hf = 0; hf < 2; ++hf)
#pragma unroll
      for (int r = 0; r < 4; ++r)
        sm[wid][mf * 16 + l4 * 4 + r][hf * 16 + l15] = pp[mf * 2 + hf][r];
  __syncthreads();
#pragma unroll
  for (int i = 0; i < 8; ++i) {
    const int p = tid * 8 + i;
    const int m = p >> 5, h = p & 31;
    const int gm = m0 + m, gh = h0 + h;
    const float gi = sm[0][m][h] + bias4h[gh];
    const float gf = sm[1][m][h] + bias4h[1024 + gh];
    const float gg = sm[2][m][h] + bias4h[2048 + gh];
    const float go = sm[3][m][h] + bias4h[3072 + gh];
    const float c  = sigf(gf) * main_c[gm * 1024 + gh] + sigf(gi) * tanhf(gg);
    const float hn = sigf(go) * tanhf(c);
    out_c[gm * 1024 + gh] = c;
    out_h[gm * 1024 + gh] = hn;
  }
}

extern "C" void kernel_launch(void* const* d_in, const int* in_sizes, int n_in,
                              void* d_out, int out_size, void* d_ws, size_t ws_size,
                              hipStream_t stream) {
  const float* input      = (const float*)d_in[0];
  const float* main_h     = (const float*)d_in[1];
  const float* main_c     = (const float*)d_in[2];
  const float* meta_h     = (const float*)d_in[3];
  const float* meta_c     = (const float*)d_in[4];
  const int*   task_index = (const int*)d_in[5];
  const float* weight_iH  = (const float*)d_in[6];
  const float* weight_HH  = (const float*)d_in[7];
  const float* weight_ih  = (const float*)d_in[8];
  const float* weight_hh  = (const float*)d_in[9];
  const float* w_hzi      = (const float*)d_in[10];
  const float* w_hzH      = (const float*)d_in[11];
  const float* w_hzb      = (const float*)d_in[12];
  const float* w_dziH     = (const float*)d_in[13];
  const float* w_dzHH     = (const float*)d_in[14];
  const float* w_bzH      = (const float*)d_in[15];
  const float* bias_i     = (const float*)d_in[16];
  const float* bias_H     = (const float*)d_in[17];
  const float* bias       = (const float*)d_in[18];
  const float* bias_hyper = (const float*)d_in[19];

  float* out        = (float*)d_out;
  float* out_main_h = out;
  float* out_main_c = out + 512 * 1024;
  float* out_meta_h = out + 2 * 512 * 1024;
  float* out_meta_c = out + 2 * 512 * 1024 + 512 * 256;

  unsigned short* ws = (unsigned short*)d_ws;

  convert_kernel<<<dim3(6208), 256, 0, stream>>>(input, main_h, meta_h, weight_ih, weight_hh,
                                                 weight_iH, weight_HH, task_index,
                                                 w_dziH, w_dzHH, w_bzH, ws);
  meta_kernel<<<dim3(256), 256, 0, stream>>>(ws, meta_c, bias_hyper, out_meta_h, out_meta_c);
  z_kernel<<<dim3(128), 192, 0, stream>>>(ws, w_hzi, w_hzH, w_hzb, bias_i, bias_H);
  main_kernel<<<dim3(256), 256, 0, stream>>>(ws, main_c, bias, out_main_h, out_main_c);
}